// Round 4
// baseline (61.280 us; speedup 1.0000x reference)
//
#include <hip/hip_runtime.h>
#include <hip/hip_bf16.h>
#include <math.h>

// Problem: B=64, C=128, H=64, W=64, HW=4096
// out   : (B,C,H,W) f32 at d_out[0];  logdet: (B,) f32 at d_out[33554432]
//
// Algebra: pool[b,l] = sum_c wbar[c]*mask[c,l]*x[b,c,l] + bbar,
//   wbar[c] = mean_o w[o,c], bbar = mean(bias)  -> 128x128 mix never built.
// logdet[b] = 64 * sum_l log g[b,l] + B*(HW/2)*sum_c log s_sig[c]
//
// Round-4: single fused kernel. prep folded in (per-block cooperative wbar
// from L2-hot w; bias + log-s_sig ride the pool shuffle tree); fin replaced
// by one atomicAdd per block (logdet zeroed via captured hipMemsetAsync).
// Output stores stay non-temporal (write-once stream).

#define EPS 1e-5f
#define NC 128
#define NHW 4096
#define NB 64
#define LT 64            // pixels per block tile
#define NLT (NHW / LT)

typedef __attribute__((ext_vector_type(4))) float f4;

__global__ __launch_bounds__(256) void fused_kernel(const float* __restrict__ x,
                                                    const float* __restrict__ w,
                                                    const float* __restrict__ bias,
                                                    const float* __restrict__ s,
                                                    const float* __restrict__ offp,
                                                    float* __restrict__ out,
                                                    float* __restrict__ logdet) {
    __shared__ float  wpart[256];   // column-sum halves of w
    __shared__ float4 pp[4][16];    // per-wave pool partials
    __shared__ float  ls[4];        // per-wave sum of log(s_sig)

    const int tid  = threadIdx.x;
    const int j    = tid & 15;      // pixel-quad index: pixels l0 + 4j .. 4j+3
    const int cg   = tid >> 4;      // channel group 0..15 (8 channels each)
    const int wave = tid >> 6;
    const int lane = tid & 63;

    const int lt = blockIdx.x;      // l-tile 0..63
    const int b  = blockIdx.y;      // batch
    const int l0 = lt * LT;         // multiple of 64 (even)

    const size_t base = (size_t)b * (NC * NHW) + (size_t)(cg * 8) * NHW + l0 + j * 4;
    const float* __restrict__ xp = x + base;

    // ---- issue the 8 float4 x loads (HBM long pole, in flight early) ----
    float4 v[8];
#pragma unroll
    for (int k = 0; k < 8; ++k)
        v[k] = *reinterpret_cast<const float4*>(xp + (size_t)k * NHW);

    // ---- cooperative wbar: thread sums 64 rows of column (tid&127) ----
    {
        const int c  = tid & 127;
        const int o0 = (tid >> 7) * 64;
        const float* __restrict__ wp = w + (size_t)o0 * NC + c;
        float a0 = 0.f, a1 = 0.f, a2 = 0.f, a3 = 0.f;
#pragma unroll
        for (int o = 0; o < 64; o += 4) {
            a0 += wp[(o + 0) * NC];
            a1 += wp[(o + 1) * NC];
            a2 += wp[(o + 2) * NC];
            a3 += wp[(o + 3) * NC];
        }
        wpart[tid] = (a0 + a1) + (a2 + a3);
    }

    // ---- per-thread channel params (L2-hot broadcasts) ----
    float ssig[8];
    float bias_part = 0.f;   // sum bias[c]/NC over my 8 channels
    float lss       = 0.f;   // sum log(s_sig[c]) over my 8 channels
#pragma unroll
    for (int k = 0; k < 8; ++k) {
        const int c  = cg * 8 + k;
        const float sg = 1.f / (1.f + __expf(-s[c])) + EPS;
        ssig[k] = sg;
        lss += __logf(sg);
        bias_part += bias[c];
    }
    bias_part *= (1.f / NC);

    __syncthreads();   // wpart ready

    // ---- pool partial over my 8 channels (bbar share pre-added) ----
    float4 acc = make_float4(bias_part, bias_part, bias_part, bias_part);
#pragma unroll
    for (int k = 0; k < 8; ++k) {
        const int c  = cg * 8 + k;
        const float wb = (wpart[c] + wpart[NC + c]) * (1.f / NC);
        if (c & 1) { acc.x += wb * v[k].x; acc.z += wb * v[k].z; }
        else       { acc.y += wb * v[k].y; acc.w += wb * v[k].w; }
    }

    // ---- reduce over the 16 channel-groups: shfl within wave, LDS across ----
#pragma unroll
    for (int off = 16; off <= 32; off <<= 1) {
        acc.x += __shfl_xor(acc.x, off);
        acc.y += __shfl_xor(acc.y, off);
        acc.z += __shfl_xor(acc.z, off);
        acc.w += __shfl_xor(acc.w, off);
        lss   += __shfl_xor(lss,   off);
    }
    if (lane < 16) pp[wave][j] = acc;   // lane==j for lane<16
    if (lane == 0) ls[wave] = lss;
    __syncthreads();

    // ---- gate (redundant per thread; VALU is idle) ----
    const float4 p0 = pp[0][j], p1 = pp[1][j], p2 = pp[2][j], p3 = pp[3][j];
    const float off0 = offp[0];
    float4 g;
    g.x = 1.f / (1.f + __expf(-(p0.x + p1.x + p2.x + p3.x + off0))) + EPS;
    g.y = 1.f / (1.f + __expf(-(p0.y + p1.y + p2.y + p3.y + off0))) + EPS;
    g.z = 1.f / (1.f + __expf(-(p0.z + p1.z + p2.z + p3.z + off0))) + EPS;
    g.w = 1.f / (1.f + __expf(-(p0.w + p1.w + p2.w + p3.w + off0))) + EPS;

    // ---- logdet contribution: 64*sum log g (this tile) + const share ----
    if (wave == 0) {
        float slg = (lane < 16)
                  ? (__logf(g.x) + __logf(g.y) + __logf(g.z) + __logf(g.w))
                  : 0.f;
#pragma unroll
        for (int off = 32; off > 0; off >>= 1) slg += __shfl_down(slg, off);
        if (lane == 0) {
            const float S = ls[0] + ls[1] + ls[2] + ls[3];  // sum_c log s_sig
            // per-b const = B*(HW/2)*S = 64*2048*S; split over 64 blocks/b
            atomicAdd(&logdet[b], 64.f * slg + 2048.f * S);
        }
    }

    // ---- scale registers and store (non-temporal: write-once stream) ----
    float* __restrict__ op = out + base;
#pragma unroll
    for (int k = 0; k < 8; ++k) {
        const int c  = cg * 8 + k;
        const float sc = ssig[k];
        f4 o;
        if (c & 1) { o.x = v[k].x * sc;  o.y = v[k].y * g.y;
                     o.z = v[k].z * sc;  o.w = v[k].w * g.w; }
        else       { o.x = v[k].x * g.x; o.y = v[k].y * sc;
                     o.z = v[k].z * g.z; o.w = v[k].w * sc; }
        __builtin_nontemporal_store(o, reinterpret_cast<f4*>(op + (size_t)k * NHW));
    }
}

extern "C" void kernel_launch(void* const* d_in, const int* in_sizes, int n_in,
                              void* d_out, int out_size, void* d_ws, size_t ws_size,
                              hipStream_t stream) {
    const float* x    = (const float*)d_in[0];
    const float* w    = (const float*)d_in[1];
    const float* bias = (const float*)d_in[2];
    const float* s    = (const float*)d_in[3];
    const float* offp = (const float*)d_in[4];

    float* out    = (float*)d_out;
    float* logdet = out + (size_t)NB * NC * NHW;

    // zero the logdet accumulators (capturable memset node)
    hipMemsetAsync(logdet, 0, NB * sizeof(float), stream);

    fused_kernel<<<dim3(NLT, NB), 256, 0, stream>>>(x, w, bias, s, offp, out, logdet);
}

// Round 5
// 58.929 us; speedup vs baseline: 1.0399x; 1.0399x over previous
//
#include <hip/hip_runtime.h>
#include <hip/hip_bf16.h>
#include <math.h>

// Problem: B=64, C=128, H=64, W=64, HW=4096
// out   : (B,C,H,W) f32 at d_out[0];  logdet: (B,) f32 at d_out[33554432]
//
// Algebra: pool[b,l] = sum_c wbar[c]*mask[c,l]*x[b,c,l] + bbar,
//   wbar[c] = mean_o w[o,c], bbar = mean(bias)  -> 128x128 mix never built.
// logdet[b] = 64 * sum_l log g[b,l] + B*(HW/2)*sum_c log s_sig[c]
//
// Round-5: two kernels. prep (1 tiny block) computes wbar/ssig/bbar AND
// initializes logdet[b] with the constant term (double precision). main is
// round-3's best-measured streaming kernel, with fin replaced by a single
// atomicAdd per block (64 tile-sums per batch). nt stores kept.

#define EPS 1e-5f
#define NC 128
#define NHW 4096
#define NB 64
#define LT 64            // pixels per block tile
#define NLT (NHW / LT)

typedef __attribute__((ext_vector_type(4))) float f4;

// ws layout (floats): [0..127] wbar, [128..255] s_sig, [256] bbar

__global__ __launch_bounds__(256) void prep_kernel(const float* __restrict__ w,
                                                   const float* __restrict__ bias,
                                                   const float* __restrict__ s,
                                                   float* __restrict__ ws,
                                                   float* __restrict__ logdet) {
    __shared__ float wpart[256];
    __shared__ float lred[NC];
    __shared__ float bred[NC];
    __shared__ float ldconst;

    const int tid = threadIdx.x;        // 256 threads
    // column c = tid&127, o-half h = tid>>7: sum 64 rows, 8 indep chains
    {
        const int c  = tid & 127;
        const int o0 = (tid >> 7) * 64;
        const float* __restrict__ wp = w + (size_t)o0 * NC + c;
        float a0 = 0.f, a1 = 0.f, a2 = 0.f, a3 = 0.f;
        float a4 = 0.f, a5 = 0.f, a6 = 0.f, a7 = 0.f;
#pragma unroll
        for (int o = 0; o < 64; o += 8) {
            a0 += wp[(o + 0) * NC];
            a1 += wp[(o + 1) * NC];
            a2 += wp[(o + 2) * NC];
            a3 += wp[(o + 3) * NC];
            a4 += wp[(o + 4) * NC];
            a5 += wp[(o + 5) * NC];
            a6 += wp[(o + 6) * NC];
            a7 += wp[(o + 7) * NC];
        }
        wpart[tid] = (((a0 + a1) + (a2 + a3)) + ((a4 + a5) + (a6 + a7)));
    }
    __syncthreads();

    if (tid < NC) {
        ws[tid] = (wpart[tid] + wpart[NC + tid]) * (1.f / NC);
        const float ssig = 1.f / (1.f + expf(-s[tid])) + EPS;
        ws[NC + tid] = ssig;
        lred[tid] = logf(ssig);
        bred[tid] = bias[tid];
    }
    __syncthreads();

    if (tid == 0) {
        double sb = 0.0, sl = 0.0;
        for (int i = 0; i < NC; ++i) { sb += (double)bred[i]; sl += (double)lred[i]; }
        ws[256] = (float)(sb / NC);
        // const term per batch: B*(HW/2)*sum_c log ssig = 64*2048*S
        ldconst = (float)((double)NB * (double)(NHW / 2) * sl);
    }
    __syncthreads();
    if (tid < NB) logdet[tid] = ldconst;   // init logdet each call
}

__global__ __launch_bounds__(256) void main_kernel(const float* __restrict__ x,
                                                   const float* __restrict__ ws,
                                                   const float* __restrict__ offp,
                                                   float* __restrict__ out,
                                                   float* __restrict__ logdet) {
    __shared__ float4 pp[4][16];   // 1 KiB: per-wave pool partials

    const int tid  = threadIdx.x;
    const int j    = tid & 15;     // pixel-quad index: pixels l0 + 4j .. 4j+3
    const int cg   = tid >> 4;     // channel group 0..15 (8 channels each)
    const int wave = tid >> 6;
    const int lane = tid & 63;

    const int lt = blockIdx.x;     // l-tile 0..63
    const int b  = blockIdx.y;     // batch
    const int l0 = lt * LT;        // multiple of 64 (even)

    const size_t base = (size_t)b * (NC * NHW) + (size_t)(cg * 8) * NHW + l0 + j * 4;
    const float* __restrict__ xp = x + base;

    // ---- load 8 float4 into registers ----
    float4 v[8];
#pragma unroll
    for (int k = 0; k < 8; ++k)
        v[k] = *reinterpret_cast<const float4*>(xp + (size_t)k * NHW);

    // ---- per-thread pool partial over its 8 channels ----
    float4 acc = make_float4(0.f, 0.f, 0.f, 0.f);
#pragma unroll
    for (int k = 0; k < 8; ++k) {
        const int c = cg * 8 + k;
        const float wb = ws[c];
        if (c & 1) { acc.x += wb * v[k].x; acc.z += wb * v[k].z; }
        else       { acc.y += wb * v[k].y; acc.w += wb * v[k].w; }
    }

    // ---- reduce over the 4 channel-groups within this wave ----
#pragma unroll
    for (int off = 16; off <= 32; off <<= 1) {
        acc.x += __shfl_xor(acc.x, off);
        acc.y += __shfl_xor(acc.y, off);
        acc.z += __shfl_xor(acc.z, off);
        acc.w += __shfl_xor(acc.w, off);
    }
    if (lane < 16) pp[wave][j] = acc;   // lane==j for lane<16
    __syncthreads();

    // ---- final pool + gate (redundant per thread; VALU is idle) ----
    const float4 p0 = pp[0][j], p1 = pp[1][j], p2 = pp[2][j], p3 = pp[3][j];
    const float cst = ws[256] + offp[0];
    float4 g;
    g.x = 1.f / (1.f + __expf(-(p0.x + p1.x + p2.x + p3.x + cst))) + EPS;
    g.y = 1.f / (1.f + __expf(-(p0.y + p1.y + p2.y + p3.y + cst))) + EPS;
    g.z = 1.f / (1.f + __expf(-(p0.z + p1.z + p2.z + p3.z + cst))) + EPS;
    g.w = 1.f / (1.f + __expf(-(p0.w + p1.w + p2.w + p3.w + cst))) + EPS;

    // ---- logdet: per-block sum of log(g), one atomicAdd per block ----
    if (wave == 0) {
        float slg = (lane < 16)
                  ? (__logf(g.x) + __logf(g.y) + __logf(g.z) + __logf(g.w))
                  : 0.f;
#pragma unroll
        for (int off = 32; off > 0; off >>= 1) slg += __shfl_down(slg, off);
        if (lane == 0) atomicAdd(&logdet[b], 64.f * slg);   // (C//2) = 64
    }

    // ---- scale registers and store (non-temporal: write-once stream) ----
    const float* __restrict__ ssig = ws + NC;
    float* __restrict__ op = out + base;
#pragma unroll
    for (int k = 0; k < 8; ++k) {
        const int c = cg * 8 + k;
        const float sc = ssig[c];
        f4 o;
        if (c & 1) { o.x = v[k].x * sc;  o.y = v[k].y * g.y;
                     o.z = v[k].z * sc;  o.w = v[k].w * g.w; }
        else       { o.x = v[k].x * g.x; o.y = v[k].y * sc;
                     o.z = v[k].z * g.z; o.w = v[k].w * sc; }
        __builtin_nontemporal_store(o, reinterpret_cast<f4*>(op + (size_t)k * NHW));
    }
}

extern "C" void kernel_launch(void* const* d_in, const int* in_sizes, int n_in,
                              void* d_out, int out_size, void* d_ws, size_t ws_size,
                              hipStream_t stream) {
    const float* x    = (const float*)d_in[0];
    const float* w    = (const float*)d_in[1];
    const float* bias = (const float*)d_in[2];
    const float* s    = (const float*)d_in[3];
    const float* offp = (const float*)d_in[4];

    float* out    = (float*)d_out;
    float* logdet = out + (size_t)NB * NC * NHW;
    float* ws     = (float*)d_ws;

    prep_kernel<<<1, 256, 0, stream>>>(w, bias, s, ws, logdet);
    main_kernel<<<dim3(NLT, NB), 256, 0, stream>>>(x, ws, offp, out, logdet);
}